// Round 27
// baseline (161.127 us; speedup 1.0000x reference)
//
#include <hip/hip_runtime.h>
#include <hip/hip_bf16.h>
#include <cstdint>

typedef short bf16x8 __attribute__((ext_vector_type(8)));
typedef float f32x4 __attribute__((ext_vector_type(4)));

// Problem constants: B=2, DIM=128, H=64, W=64, DH=32, HEADS=4, K=7
#define NTOK 8192
#define QSCALE 0.17677669529663687f

__device__ inline float b2f(short s) {
  return __uint_as_float(((unsigned)(unsigned short)s) << 16);
}
__device__ inline short f2bs(float x) {
  __hip_bfloat16 b = __float2bfloat16(x);
  return *reinterpret_cast<short*>(&b);
}
__device__ inline bf16x8 ld8(const short* p) {
  short4 lo = *reinterpret_cast<const short4*>(p);
  short4 hi = *reinterpret_cast<const short4*>(p + 4);
  bf16x8 r;
  r[0] = lo.x; r[1] = lo.y; r[2] = lo.z; r[3] = lo.w;
  r[4] = hi.x; r[5] = hi.y; r[6] = hi.z; r[7] = hi.w;
  return r;
}
__device__ inline bf16x8 cvt8(float4 a, float4 c) {
  bf16x8 r;
  r[0] = f2bs(a.x); r[1] = f2bs(a.y); r[2] = f2bs(a.z); r[3] = f2bs(a.w);
  r[4] = f2bs(c.x); r[5] = f2bs(c.y); r[6] = f2bs(c.z); r[7] = f2bs(c.w);
  return r;
}

// ---------------- Single-kernel pipeline: qkvcw phase -> flag sync -> attn+tail ----------------
// Co-residency: grid 512 = 2 blocks/CU x 256 CU, lb(512,4), LDS 77.6KB <= 80KB
// (guide-blessed capacity rule) -> producers never starve; flag spin is safe.
// Phase A output visibility: per-thread __threadfence + barrier, then tid0
// device-scope release store of flags[swz] and counter bump. Phase B acquires
// its 28 producer flags (agent scope -> L2 invalidate per gfx94x+ model),
// runs attention overlapped with phase-A stragglers, then waits cnt==512
// (tail weights wb complete) before the tail GEMM chain.
#define NB 98
#define VP 108
#define VPD 54
#define PP 132
#define VTSH 13824  // shorts per Vt buffer (128*VP)
__global__ __launch_bounds__(512, 4) void k_mega(
    const float* __restrict__ x, const float* __restrict__ g1,
    const float* __restrict__ be1, const float* __restrict__ qkv_b,
    const float* __restrict__ qkv_w, const float* __restrict__ pw,
    const float* __restrict__ w1f, const float* __restrict__ w2f,
    const float* __restrict__ w3f, __hip_bfloat16* __restrict__ wb,
    __hip_bfloat16* __restrict__ qkvb, const float* __restrict__ rpb,
    const float* __restrict__ bproj,
    const float* __restrict__ g2, const float* __restrict__ be2,
    const float* __restrict__ b1,
    const float* __restrict__ g3, const float* __restrict__ be3,
    const float* __restrict__ b2,
    const float* __restrict__ g4, const float* __restrict__ be4,
    const float* __restrict__ b3, float* __restrict__ out,
    int* __restrict__ flags, int* __restrict__ cnt) {
  __shared__ __align__(16) short smem[2 * VTSH + 2 * 4 * 8 * PP];
  __shared__ __align__(16) __hip_bfloat16 abuf[16][136];
  __shared__ float2 red[8][16];
  int t = threadIdx.x;
  int bid = blockIdx.x;
  int swz = (bid & 7) * 64 + (bid >> 3);  // bijective XCD swizzle (512%8==0)
  int m0 = swz * 16;
  int b = m0 >> 12, hq = (m0 >> 6) & 63;
  int hs = min(max(hq - 3, 0), 57);

  // ================= PHASE A: weight convert + LN1 + QKV GEMM =================
  {
    char* lbase = (char*)smem;
    float(*xt)[17] = reinterpret_cast<float(*)[17]>(lbase);               // 8704B
    __hip_bfloat16(*at)[136] =
        reinterpret_cast<__hip_bfloat16(*)[136]>(lbase + 8704);           // 4352B
    __hip_bfloat16(*qt)[392] =
        reinterpret_cast<__hip_bfloat16(*)[392]>(lbase + 8704 + 4352);    // 12544B
    if (t < 128) {
      int ci = bid * 128 + t;
      float cv;
      if (ci < 16384) cv = pw[ci];
      else if (ci < 32768) cv = w1f[ci - 16384];
      else if (ci < 49152) cv = w2f[ci - 32768];
      else cv = w3f[ci - 49152];
      wb[ci] = __float2bfloat16(cv);
    }
    int p0 = m0 & 4095;
    const float* xb = x + (size_t)b * 524288;
    int tw = t & 15, th = t >> 4;
#pragma unroll
    for (int i = 0; i < 4; ++i) {
      int c = i * 32 + th;
      xt[c][tw] = xb[c * 4096 + p0 + tw];
    }
    __syncthreads();
    int wid = t >> 6, lane = t & 63;
    float gg0 = g1[lane], gg1v = g1[lane + 64];
    float bb0 = be1[lane], bb1 = be1[lane + 64];
#pragma unroll
    for (int it = 0; it < 2; ++it) {
      int tt = wid * 2 + it;
      float v0 = xt[lane][tt], v1 = xt[lane + 64][tt];
      float s = v0 + v1, sq = v0 * v0 + v1 * v1;
#pragma unroll
      for (int off = 32; off; off >>= 1) {
        s += __shfl_xor(s, off);
        sq += __shfl_xor(sq, off);
      }
      float mu = s * (1.f / 128.f);
      float var = sq * (1.f / 128.f) - mu * mu;
      float rs = rsqrtf(var + 1e-5f);
      at[tt][lane] = __float2bfloat16((v0 - mu) * rs * gg0 + bb0);
      at[tt][lane + 64] = __float2bfloat16((v1 - mu) * rs * gg1v + bb1);
    }
    __syncthreads();
    int lr = lane & 15, kg = lane >> 4;
    bf16x8 af[4];
#pragma unroll
    for (int ks = 0; ks < 4; ++ks)
      af[ks] = *reinterpret_cast<const bf16x8*>(&at[lr][ks * 32 + kg * 8]);
    f32x4 acc[3];
#pragma unroll
    for (int nf = 0; nf < 3; ++nf) acc[nf] = f32x4{0, 0, 0, 0};
#pragma unroll
    for (int nf = 0; nf < 3; ++nf) {
      int o = wid * 48 + nf * 16 + lr;
      const float* wp = qkv_w + o * 128 + kg * 8;
#pragma unroll
      for (int ks = 0; ks < 4; ++ks) {
        float4 wa = *reinterpret_cast<const float4*>(wp + ks * 32);
        float4 wc = *reinterpret_cast<const float4*>(wp + ks * 32 + 4);
        acc[nf] = __builtin_amdgcn_mfma_f32_16x16x32_bf16(af[ks], cvt8(wa, wc),
                                                          acc[nf], 0, 0, 0);
      }
    }
#pragma unroll
    for (int nf = 0; nf < 3; ++nf) {
      int o = wid * 48 + nf * 16 + lr;
      float bv = qkv_b[o];
      float qsc = (o < 128) ? QSCALE : 1.f;
#pragma unroll
      for (int rr = 0; rr < 4; ++rr)
        qt[kg * 4 + rr][o] = __float2bfloat16((acc[nf][rr] + bv) * qsc);
    }
    __syncthreads();
    for (int i = t; i < 768; i += 512) {  // 16 rows x 48 chunks of 16B
      int row = i / 48, col = i - row * 48;
      *reinterpret_cast<uint4*>(qkvb + (size_t)(m0 + row) * 384 + col * 8) =
          *reinterpret_cast<const uint4*>(&qt[row][col * 8]);
    }
  }
  // ---- publish phase A ----
  __threadfence();
  __syncthreads();
  if (t == 0) {
    __hip_atomic_store(&flags[swz], 1, __ATOMIC_RELEASE, __HIP_MEMORY_SCOPE_AGENT);
    __hip_atomic_fetch_add(cnt, 1, __ATOMIC_RELEASE, __HIP_MEMORY_SCOPE_AGENT);
  }

  // ---- wait for the 28 producer units of this block's attention window ----
  {
    int f0 = b * 256 + hs * 4;  // 7 rows x 4 units/row
    if (t < 28)
      while (__hip_atomic_load(&flags[f0 + t], __ATOMIC_ACQUIRE,
                               __HIP_MEMORY_SCOPE_AGENT) == 0) {}
    __syncthreads();
  }

  // ================= PHASE B: attention + tail (R26 body) =================
  const short* qs = (const short*)qkvb;
  int tid = t;
  const __hip_bfloat16* wproj = wb;
  const __hip_bfloat16* w1 = wb + 16384;
  const __hip_bfloat16* w2 = wb + 32768;
  const __hip_bfloat16* w3 = wb + 49152;

  {
    int half = tid >> 8;
    int tl = tid & 255;
    int c0h = (m0 & 63) + half * 8;
    int csh = min(max(c0h - 3, 0), 50);
    unsigned* VtD = (unsigned*)(smem + half * VTSH);
    int g2i = tl >> 6, rp = tl & 63;
    if (rp < 49) {
      int r0 = rp * 2, r1 = r0 + 1;
      int rh0 = r0 / 14, rc0 = r0 - rh0 * 14;
      int rh1 = r1 / 14, rc1 = r1 - rh1 * 14;
      int tr0 = b * 4096 + (hs + rh0) * 64 + min(csh + rc0, 63);
      int tr1 = b * 4096 + (hs + rh1) * 64 + min(csh + rc1, 63);
#pragma unroll
      for (int gg = 0; gg < 4; ++gg) {
        int d0 = (g2i * 4 + gg) * 8;
        const short* p0 = qs + (size_t)tr0 * 384 + 256 + d0;
        const short* p1 = qs + (size_t)tr1 * 384 + 256 + d0;
        short4 a0 = *(const short4*)p0, a1 = *(const short4*)(p0 + 4);
        short4 c0v = *(const short4*)p1, c1 = *(const short4*)(p1 + 4);
        unsigned bse = (unsigned)d0 * VPD + rp;
        VtD[bse + 0 * VPD] = (unsigned short)a0.x | ((unsigned)(unsigned short)c0v.x << 16);
        VtD[bse + 1 * VPD] = (unsigned short)a0.y | ((unsigned)(unsigned short)c0v.y << 16);
        VtD[bse + 2 * VPD] = (unsigned short)a0.z | ((unsigned)(unsigned short)c0v.z << 16);
        VtD[bse + 3 * VPD] = (unsigned short)a0.w | ((unsigned)(unsigned short)c0v.w << 16);
        VtD[bse + 4 * VPD] = (unsigned short)a1.x | ((unsigned)(unsigned short)c1.x << 16);
        VtD[bse + 5 * VPD] = (unsigned short)a1.y | ((unsigned)(unsigned short)c1.y << 16);
        VtD[bse + 6 * VPD] = (unsigned short)a1.z | ((unsigned)(unsigned short)c1.z << 16);
        VtD[bse + 7 * VPD] = (unsigned short)a1.w | ((unsigned)(unsigned short)c1.w << 16);
      }
    }
    for (int i = tl; i < 128 * 5; i += 256) {
      int d = i / 5, j = i - d * 5;
      VtD[d * VPD + 49 + j] = 0;
    }
  }

  int wid = tid >> 6, lane = tid & 63;
  int sst = wid >> 2, h = wid & 3;
  int lr = lane & 15, kg = lane >> 4;
  int m0s = m0 + sst * 8;
  int c0s = (m0 & 63) + sst * 8;
  int cs0 = min(max(c0s - 3, 0), 50);
  int qrow = min(m0s + lr, NTOK - 1);
  bf16x8 aq = *reinterpret_cast<const bf16x8*>(qs + (size_t)qrow * 384 + h * 32 + kg * 8);
  f32x4 sc[7];
#pragma unroll
  for (int nt = 0; nt < 7; ++nt) {
    int nbr = nt * 16 + lr;
    int rw = min(nbr, NB - 1);
    int rh = rw / 14, rc = rw - rh * 14;
    int tn = b * 4096 + (hs + rh) * 64 + min(cs0 + rc, 63);
    bf16x8 bk = *reinterpret_cast<const bf16x8*>(qs + (size_t)tn * 384 + 128 + h * 32 + kg * 8);
    sc[nt] = __builtin_amdgcn_mfma_f32_16x16x32_bf16(aq, bk, f32x4{0, 0, 0, 0}, 0, 0, 0);
  }
  int offv[4], cmt[4];
#pragma unroll
  for (int rr = 0; rr < 4; ++rr) {
    int ct = c0s + kg * 4 + rr;
    int ws0 = min(max(ct - 3, 0), 57);
    offv[rr] = ws0 - cs0;
    cmt[rr] = cs0 + 6 - ct;
  }
  float mx[4] = {-3e38f, -3e38f, -3e38f, -3e38f};
#pragma unroll
  for (int nt = 0; nt < 7; ++nt) {
    int nbr = nt * 16 + lr;
    int rh = nbr / 14, rc = nbr - rh * 14;
    bool vn = nbr < NB;
    int ribase = h * 169 + (hs - hq + 6 + rh) * 13 + rc;
#pragma unroll
    for (int rr = 0; rr < 4; ++rr) {
      float v = -1e30f;
      if (vn && (unsigned)(rc - offv[rr]) < 7u) v = sc[nt][rr] + rpb[ribase + cmt[rr]];
      sc[nt][rr] = v;
      mx[rr] = fmaxf(mx[rr], v);
    }
  }
#pragma unroll
  for (int rr = 0; rr < 4; ++rr) {
    mx[rr] = fmaxf(mx[rr], __shfl_xor(mx[rr], 1));
    mx[rr] = fmaxf(mx[rr], __shfl_xor(mx[rr], 2));
    mx[rr] = fmaxf(mx[rr], __shfl_xor(mx[rr], 4));
    mx[rr] = fmaxf(mx[rr], __shfl_xor(mx[rr], 8));
  }
  float sum[4] = {0.f, 0.f, 0.f, 0.f};
#pragma unroll
  for (int nt = 0; nt < 7; ++nt)
#pragma unroll
    for (int rr = 0; rr < 4; ++rr) {
      float e = __expf(sc[nt][rr] - mx[rr]);
      sc[nt][rr] = e;
      sum[rr] += e;
    }
#pragma unroll
  for (int rr = 0; rr < 4; ++rr) {
    sum[rr] += __shfl_xor(sum[rr], 1);
    sum[rr] += __shfl_xor(sum[rr], 2);
    sum[rr] += __shfl_xor(sum[rr], 4);
    sum[rr] += __shfl_xor(sum[rr], 8);
  }
  short* Ph = smem + 2 * VTSH + ((sst * 4 + h) * 8) * PP;
  if (kg < 2) {
#pragma unroll
    for (int rr = 0; rr < 4; ++rr) {
      float inv = 1.f / sum[rr];
      int tok = kg * 4 + rr;
#pragma unroll
      for (int nt = 0; nt < 7; ++nt)
        Ph[tok * PP + nt * 16 + lr] = f2bs(sc[nt][rr] * inv);
      Ph[tok * PP + 112 + lr] = 0;
      Ph[tok * PP + 128 + (lr & 3)] = 0;
    }
  }
  __syncthreads();  // Vt (both strips) staged + P visible
  {
    const short* Vts = smem + sst * VTSH;
    f32x4 o2[2] = {f32x4{0, 0, 0, 0}, f32x4{0, 0, 0, 0}};
#pragma unroll
    for (int kt = 0; kt < 4; ++kt) {
      bf16x8 ap = ld8(Ph + (lr & 7) * PP + kt * 32 + kg * 8);
#pragma unroll
      for (int dt = 0; dt < 2; ++dt) {
        bf16x8 bv = ld8(Vts + (h * 32 + dt * 16 + lr) * VP + kt * 32 + kg * 8);
        o2[dt] = __builtin_amdgcn_mfma_f32_16x16x32_bf16(ap, bv, o2[dt], 0, 0, 0);
      }
    }
    if (kg < 2) {
#pragma unroll
      for (int dt = 0; dt < 2; ++dt)
#pragma unroll
        for (int rr = 0; rr < 4; ++rr)
          abuf[sst * 8 + kg * 4 + rr][h * 32 + dt * 16 + lr] =
              __float2bfloat16(o2[dt][rr]);
    }
  }
  __syncthreads();  // abuf complete

  // ---- wait for ALL phase A (tail weights wb fully converted) ----
  if (t == 0)
    while (__hip_atomic_load(cnt, __ATOMIC_ACQUIRE, __HIP_MEMORY_SCOPE_AGENT) < 512) {}
  __syncthreads();

  f32x4 acc;
  float x2f[4];

  auto gemm_lds = [&](const __hip_bfloat16* W) {
    bf16x8 af[4];
#pragma unroll
    for (int ks = 0; ks < 4; ++ks)
      af[ks] = *reinterpret_cast<const bf16x8*>(&abuf[lr][ks * 32 + kg * 8]);
    int o = wid * 16 + lr;
    const __hip_bfloat16* wp = W + o * 128 + kg * 8;
    acc = f32x4{0, 0, 0, 0};
#pragma unroll
    for (int ks = 0; ks < 4; ++ks) {
      bf16x8 bfr = *reinterpret_cast<const bf16x8*>(wp + ks * 32);
      acc = __builtin_amdgcn_mfma_f32_16x16x32_bf16(af[ks], bfr, acc, 0, 0, 0);
    }
  };
  auto ln_store = [&](const float* g, const float* be) {
    float ps[4], pq[4];
#pragma unroll
    for (int rr = 0; rr < 4; ++rr) {
      ps[rr] = acc[rr];
      pq[rr] = acc[rr] * acc[rr];
    }
#pragma unroll
    for (int rr = 0; rr < 4; ++rr)
#pragma unroll
      for (int off = 1; off < 16; off <<= 1) {
        ps[rr] += __shfl_xor(ps[rr], off);
        pq[rr] += __shfl_xor(pq[rr], off);
      }
    if (lr == 0)
#pragma unroll
      for (int rr = 0; rr < 4; ++rr)
        red[wid][kg * 4 + rr] = make_float2(ps[rr], pq[rr]);
    __syncthreads();
    float mu[4], rs[4];
#pragma unroll
    for (int rr = 0; rr < 4; ++rr) {
      int r16 = kg * 4 + rr;
      float ssum = 0.f, qsum = 0.f;
#pragma unroll
      for (int w = 0; w < 8; ++w) {
        float2 a = red[w][r16];
        ssum += a.x;
        qsum += a.y;
      }
      mu[rr] = ssum * (1.f / 128.f);
      float var = qsum * (1.f / 128.f) - mu[rr] * mu[rr];
      rs[rr] = rsqrtf(var + 1e-5f);
    }
    int o = wid * 16 + lr;
    float gv = g[o], bev = be[o];
#pragma unroll
    for (int rr = 0; rr < 4; ++rr)
      abuf[kg * 4 + rr][o] =
          __float2bfloat16((acc[rr] - mu[rr]) * rs[rr] * gv + bev);
    __syncthreads();
  };

  gemm_lds(wproj);
  {
    float bv = bproj[wid * 16 + lr];
#pragma unroll
    for (int rr = 0; rr < 4; ++rr) acc[rr] += bv;
  }
  ln_store(g2, be2);

  gemm_lds(w1);
  {
    int o = wid * 16 + lr;
    float bv = b1[o];
#pragma unroll
    for (int rr = 0; rr < 4; ++rr) {
      int m = m0 + kg * 4 + rr;
      float v = acc[rr] + bv +
                x[(size_t)(m >> 12) * 524288 + (size_t)o * 4096 + (m & 4095)];
      x2f[rr] = v;
      acc[rr] = v;
    }
  }
  ln_store(g3, be3);

  gemm_lds(w2);
  {
    float bv = b2[wid * 16 + lr];
#pragma unroll
    for (int rr = 0; rr < 4; ++rr) acc[rr] = fmaxf(acc[rr] + bv, 0.f);
  }
  ln_store(g4, be4);

  gemm_lds(w3);
  {
    int o = wid * 16 + lr;
    float bv = b3[o];
#pragma unroll
    for (int rr = 0; rr < 4; ++rr) {
      int m = m0 + kg * 4 + rr;
      float v = acc[rr] + bv + x2f[rr];
      int bb = m >> 12, hw = m & 4095;
      out[(size_t)bb * 524288 + o * 4096 + hw] = v;
    }
  }
}

// ---------------- launch ----------------
extern "C" void kernel_launch(void* const* d_in, const int* in_sizes, int n_in,
                              void* d_out, int out_size, void* d_ws,
                              size_t ws_size, hipStream_t stream) {
  const float* x = (const float*)d_in[0];
  const float* g1 = (const float*)d_in[1];
  const float* be1 = (const float*)d_in[2];
  const float* g2 = (const float*)d_in[3];
  const float* be2 = (const float*)d_in[4];
  const float* g3 = (const float*)d_in[5];
  const float* be3 = (const float*)d_in[6];
  const float* g4 = (const float*)d_in[7];
  const float* be4 = (const float*)d_in[8];
  const float* qkv_w = (const float*)d_in[9];
  const float* qkv_b = (const float*)d_in[10];
  const float* rpb = (const float*)d_in[11];
  const float* proj_w = (const float*)d_in[12];
  const float* proj_b = (const float*)d_in[13];
  const float* w1 = (const float*)d_in[14];
  const float* bl1 = (const float*)d_in[15];
  const float* w2 = (const float*)d_in[16];
  const float* bl2 = (const float*)d_in[17];
  const float* w3 = (const float*)d_in[18];
  const float* bl3 = (const float*)d_in[19];

  char* ws = (char*)d_ws;
  __hip_bfloat16* wb = (__hip_bfloat16*)ws;               // [65536] tail weights bf16
  int* flags = (int*)(ws + 262144);                       // [512] + cnt
  int* cnt = flags + 512;
  __hip_bfloat16* qkvb = (__hip_bfloat16*)(ws + 4456448); // [8192][384] bf16

  hipMemsetAsync(flags, 0, 513 * sizeof(int), stream);
  k_mega<<<512, 512, 0, stream>>>(x, g1, be1, qkv_b, qkv_w, proj_w, w1, w2, w3,
                                  wb, qkvb, rpb, proj_b, g2, be2, bl1, g3, be3,
                                  bl2, g4, be4, bl3, (float*)d_out, flags, cnt);
}

// Round 28
// 45.572 us; speedup vs baseline: 3.5357x; 3.5357x over previous
//
#include <hip/hip_runtime.h>
#include <hip/hip_bf16.h>
#include <cstdint>

typedef short bf16x8 __attribute__((ext_vector_type(8)));
typedef float f32x4 __attribute__((ext_vector_type(4)));

// Problem constants: B=2, DIM=128, H=64, W=64, DH=32, HEADS=4, K=7
#define NTOK 8192
#define QSCALE 0.17677669529663687f

__device__ inline float b2f(short s) {
  return __uint_as_float(((unsigned)(unsigned short)s) << 16);
}
__device__ inline short f2bs(float x) {
  __hip_bfloat16 b = __float2bfloat16(x);
  return *reinterpret_cast<short*>(&b);
}
__device__ inline bf16x8 ld8(const short* p) {
  short4 lo = *reinterpret_cast<const short4*>(p);
  short4 hi = *reinterpret_cast<const short4*>(p + 4);
  bf16x8 r;
  r[0] = lo.x; r[1] = lo.y; r[2] = lo.z; r[3] = lo.w;
  r[4] = hi.x; r[5] = hi.y; r[6] = hi.z; r[7] = hi.w;
  return r;
}
__device__ inline bf16x8 cvt8(float4 a, float4 c) {
  bf16x8 r;
  r[0] = f2bs(a.x); r[1] = f2bs(a.y); r[2] = f2bs(a.z); r[3] = f2bs(a.w);
  r[4] = f2bs(c.x); r[5] = f2bs(c.y); r[6] = f2bs(c.z); r[7] = f2bs(c.w);
  return r;
}

// ---------------- K1: weight convert + NCHW->NHWC + LN1 + QKV GEMM ----------------
// R24: XCD swizzle matches k_fuse3 (producer/consumer L2 locality, -4us).
// R26: r-buffer write removed — fuse3 reads the residual directly from x.
// R27 (mega-kernel with flag sync) regressed 3.5x — kernel-boundary sync is
// cheaper than device-scope spin sync on this chip; this is the champion.
__global__ __launch_bounds__(512) void k_qkvcw(
    const float* __restrict__ x, const float* __restrict__ g,
    const float* __restrict__ be, const float* __restrict__ qkv_b,
    const float* __restrict__ qkv_w, const float* __restrict__ pw,
    const float* __restrict__ w1f, const float* __restrict__ w2f,
    const float* __restrict__ w3f, __hip_bfloat16* __restrict__ wb,
    __hip_bfloat16* __restrict__ qkvb) {
  __shared__ float xt[128][17];
  __shared__ __hip_bfloat16 at[16][136];
  __shared__ __align__(16) __hip_bfloat16 qt[16][392];  // 784B rows = 49x16B
  int t = threadIdx.x;
  if (t < 128) {
    int ci = blockIdx.x * 128 + t;
    float cv;
    if (ci < 16384) cv = pw[ci];
    else if (ci < 32768) cv = w1f[ci - 16384];
    else if (ci < 49152) cv = w2f[ci - 32768];
    else cv = w3f[ci - 49152];
    wb[ci] = __float2bfloat16(cv);
  }
  int bid = blockIdx.x;
  int swz = (bid & 7) * 64 + (bid >> 3);  // match fuse3's XCD swizzle
  int m0 = swz * 16;
  int b = m0 >> 12;
  int p0 = m0 & 4095;
  const float* xb = x + (size_t)b * 524288;
  int tw = t & 15, th = t >> 4;
#pragma unroll
  for (int i = 0; i < 4; ++i) {
    int c = i * 32 + th;
    xt[c][tw] = xb[c * 4096 + p0 + tw];
  }
  __syncthreads();
  int wid = t >> 6, lane = t & 63;
  float gg0 = g[lane], gg1 = g[lane + 64];
  float bb0 = be[lane], bb1 = be[lane + 64];
#pragma unroll
  for (int it = 0; it < 2; ++it) {
    int tt = wid * 2 + it;
    float v0 = xt[lane][tt], v1 = xt[lane + 64][tt];
    float s = v0 + v1, sq = v0 * v0 + v1 * v1;
#pragma unroll
    for (int off = 32; off; off >>= 1) {
      s += __shfl_xor(s, off);
      sq += __shfl_xor(sq, off);
    }
    float mu = s * (1.f / 128.f);
    float var = sq * (1.f / 128.f) - mu * mu;
    float rs = rsqrtf(var + 1e-5f);
    at[tt][lane] = __float2bfloat16((v0 - mu) * rs * gg0 + bb0);
    at[tt][lane + 64] = __float2bfloat16((v1 - mu) * rs * gg1 + bb1);
  }
  __syncthreads();
  int lr = lane & 15, kg = lane >> 4;
  bf16x8 af[4];
#pragma unroll
  for (int ks = 0; ks < 4; ++ks)
    af[ks] = *reinterpret_cast<const bf16x8*>(&at[lr][ks * 32 + kg * 8]);
  f32x4 acc[3];
#pragma unroll
  for (int nf = 0; nf < 3; ++nf) acc[nf] = f32x4{0, 0, 0, 0};
#pragma unroll
  for (int nf = 0; nf < 3; ++nf) {
    int o = wid * 48 + nf * 16 + lr;
    const float* wp = qkv_w + o * 128 + kg * 8;
#pragma unroll
    for (int ks = 0; ks < 4; ++ks) {
      float4 wa = *reinterpret_cast<const float4*>(wp + ks * 32);
      float4 wc = *reinterpret_cast<const float4*>(wp + ks * 32 + 4);
      acc[nf] = __builtin_amdgcn_mfma_f32_16x16x32_bf16(af[ks], cvt8(wa, wc),
                                                        acc[nf], 0, 0, 0);
    }
  }
  // epilogue: LDS tile, then coalesced 16B-chunk writes (R25)
#pragma unroll
  for (int nf = 0; nf < 3; ++nf) {
    int o = wid * 48 + nf * 16 + lr;
    float bv = qkv_b[o];
    float qs = (o < 128) ? QSCALE : 1.f;
#pragma unroll
    for (int rr = 0; rr < 4; ++rr)
      qt[kg * 4 + rr][o] = __float2bfloat16((acc[nf][rr] + bv) * qs);
  }
  __syncthreads();
  for (int i = t; i < 768; i += 512) {  // 16 rows x 48 chunks of 16B
    int row = i / 48, col = i - row * 48;
    *reinterpret_cast<uint4*>(qkvb + (size_t)(m0 + row) * 384 + col * 8) =
        *reinterpret_cast<const uint4*>(&qt[row][col * 8]);
  }
}

// ---------------- K2: fused attn (2 strips, wave=(strip,head)) + tail, 16 tok/block ----------------
// (R18-proven, R24 swizzle-aligned; R26: residual read directly from x)
#define NB 98
#define VP 108
#define VPD 54
#define PP 132
#define VTSH 13824  // shorts per Vt buffer (128*VP)
__global__ __launch_bounds__(512, 4) void k_fuse3(
    const __hip_bfloat16* __restrict__ qkvb, const float* __restrict__ rpb,
    const float* __restrict__ x, const __hip_bfloat16* __restrict__ wb,
    const float* __restrict__ bproj,
    const float* __restrict__ g2, const float* __restrict__ be2,
    const float* __restrict__ b1,
    const float* __restrict__ g3, const float* __restrict__ be3,
    const float* __restrict__ b2,
    const float* __restrict__ g4, const float* __restrict__ be4,
    const float* __restrict__ b3, float* __restrict__ out) {
  __shared__ __align__(16) short smem[2 * VTSH + 2 * 4 * 8 * PP];
  __shared__ __align__(16) __hip_bfloat16 abuf[16][136];
  __shared__ float2 red[8][16];
  const short* qs = (const short*)qkvb;
  int tid = threadIdx.x;
  int bid = blockIdx.x;
  int swz = (bid & 7) * 64 + (bid >> 3);  // bijective XCD swizzle (512%8==0)
  int m0 = swz * 16;
  int b = m0 >> 12, hq = (m0 >> 6) & 63;
  int hs = min(max(hq - 3, 0), 57);
  const __hip_bfloat16* wproj = wb;
  const __hip_bfloat16* w1 = wb + 16384;
  const __hip_bfloat16* w2 = wb + 32768;
  const __hip_bfloat16* w3 = wb + 49152;

  {
    int half = tid >> 8;
    int tl = tid & 255;
    int c0h = (m0 & 63) + half * 8;
    int csh = min(max(c0h - 3, 0), 50);
    unsigned* VtD = (unsigned*)(smem + half * VTSH);
    int g2i = tl >> 6, rp = tl & 63;
    if (rp < 49) {
      int r0 = rp * 2, r1 = r0 + 1;
      int rh0 = r0 / 14, rc0 = r0 - rh0 * 14;
      int rh1 = r1 / 14, rc1 = r1 - rh1 * 14;
      int tr0 = b * 4096 + (hs + rh0) * 64 + min(csh + rc0, 63);
      int tr1 = b * 4096 + (hs + rh1) * 64 + min(csh + rc1, 63);
#pragma unroll
      for (int gg = 0; gg < 4; ++gg) {
        int d0 = (g2i * 4 + gg) * 8;
        const short* p0 = qs + (size_t)tr0 * 384 + 256 + d0;
        const short* p1 = qs + (size_t)tr1 * 384 + 256 + d0;
        short4 a0 = *(const short4*)p0, a1 = *(const short4*)(p0 + 4);
        short4 c0v = *(const short4*)p1, c1 = *(const short4*)(p1 + 4);
        unsigned bse = (unsigned)d0 * VPD + rp;
        VtD[bse + 0 * VPD] = (unsigned short)a0.x | ((unsigned)(unsigned short)c0v.x << 16);
        VtD[bse + 1 * VPD] = (unsigned short)a0.y | ((unsigned)(unsigned short)c0v.y << 16);
        VtD[bse + 2 * VPD] = (unsigned short)a0.z | ((unsigned)(unsigned short)c0v.z << 16);
        VtD[bse + 3 * VPD] = (unsigned short)a0.w | ((unsigned)(unsigned short)c0v.w << 16);
        VtD[bse + 4 * VPD] = (unsigned short)a1.x | ((unsigned)(unsigned short)c1.x << 16);
        VtD[bse + 5 * VPD] = (unsigned short)a1.y | ((unsigned)(unsigned short)c1.y << 16);
        VtD[bse + 6 * VPD] = (unsigned short)a1.z | ((unsigned)(unsigned short)c1.z << 16);
        VtD[bse + 7 * VPD] = (unsigned short)a1.w | ((unsigned)(unsigned short)c1.w << 16);
      }
    }
    for (int i = tl; i < 128 * 5; i += 256) {
      int d = i / 5, j = i - d * 5;
      VtD[d * VPD + 49 + j] = 0;
    }
  }

  int wid = tid >> 6, lane = tid & 63;
  int sst = wid >> 2, h = wid & 3;
  int lr = lane & 15, kg = lane >> 4;
  int m0s = m0 + sst * 8;
  int c0s = (m0 & 63) + sst * 8;
  int cs0 = min(max(c0s - 3, 0), 50);
  int qrow = min(m0s + lr, NTOK - 1);
  bf16x8 aq = *reinterpret_cast<const bf16x8*>(qs + (size_t)qrow * 384 + h * 32 + kg * 8);
  f32x4 sc[7];
#pragma unroll
  for (int nt = 0; nt < 7; ++nt) {
    int nbr = nt * 16 + lr;
    int rw = min(nbr, NB - 1);
    int rh = rw / 14, rc = rw - rh * 14;
    int tn = b * 4096 + (hs + rh) * 64 + min(cs0 + rc, 63);
    bf16x8 bk = *reinterpret_cast<const bf16x8*>(qs + (size_t)tn * 384 + 128 + h * 32 + kg * 8);
    sc[nt] = __builtin_amdgcn_mfma_f32_16x16x32_bf16(aq, bk, f32x4{0, 0, 0, 0}, 0, 0, 0);
  }
  int offv[4], cmt[4];
#pragma unroll
  for (int rr = 0; rr < 4; ++rr) {
    int ct = c0s + kg * 4 + rr;
    int ws0 = min(max(ct - 3, 0), 57);
    offv[rr] = ws0 - cs0;
    cmt[rr] = cs0 + 6 - ct;
  }
  float mx[4] = {-3e38f, -3e38f, -3e38f, -3e38f};
#pragma unroll
  for (int nt = 0; nt < 7; ++nt) {
    int nbr = nt * 16 + lr;
    int rh = nbr / 14, rc = nbr - rh * 14;
    bool vn = nbr < NB;
    int ribase = h * 169 + (hs - hq + 6 + rh) * 13 + rc;
#pragma unroll
    for (int rr = 0; rr < 4; ++rr) {
      float v = -1e30f;
      if (vn && (unsigned)(rc - offv[rr]) < 7u) v = sc[nt][rr] + rpb[ribase + cmt[rr]];
      sc[nt][rr] = v;
      mx[rr] = fmaxf(mx[rr], v);
    }
  }
#pragma unroll
  for (int rr = 0; rr < 4; ++rr) {
    mx[rr] = fmaxf(mx[rr], __shfl_xor(mx[rr], 1));
    mx[rr] = fmaxf(mx[rr], __shfl_xor(mx[rr], 2));
    mx[rr] = fmaxf(mx[rr], __shfl_xor(mx[rr], 4));
    mx[rr] = fmaxf(mx[rr], __shfl_xor(mx[rr], 8));
  }
  float sum[4] = {0.f, 0.f, 0.f, 0.f};
#pragma unroll
  for (int nt = 0; nt < 7; ++nt)
#pragma unroll
    for (int rr = 0; rr < 4; ++rr) {
      float e = __expf(sc[nt][rr] - mx[rr]);
      sc[nt][rr] = e;
      sum[rr] += e;
    }
#pragma unroll
  for (int rr = 0; rr < 4; ++rr) {
    sum[rr] += __shfl_xor(sum[rr], 1);
    sum[rr] += __shfl_xor(sum[rr], 2);
    sum[rr] += __shfl_xor(sum[rr], 4);
    sum[rr] += __shfl_xor(sum[rr], 8);
  }
  short* Ph = smem + 2 * VTSH + ((sst * 4 + h) * 8) * PP;
  if (kg < 2) {
#pragma unroll
    for (int rr = 0; rr < 4; ++rr) {
      float inv = 1.f / sum[rr];
      int tok = kg * 4 + rr;
#pragma unroll
      for (int nt = 0; nt < 7; ++nt)
        Ph[tok * PP + nt * 16 + lr] = f2bs(sc[nt][rr] * inv);
      Ph[tok * PP + 112 + lr] = 0;
      Ph[tok * PP + 128 + (lr & 3)] = 0;
    }
  }
  __syncthreads();  // Vt (both strips) staged + P visible
  {
    const short* Vts = smem + sst * VTSH;
    f32x4 o2[2] = {f32x4{0, 0, 0, 0}, f32x4{0, 0, 0, 0}};
#pragma unroll
    for (int kt = 0; kt < 4; ++kt) {
      bf16x8 ap = ld8(Ph + (lr & 7) * PP + kt * 32 + kg * 8);
#pragma unroll
      for (int dt = 0; dt < 2; ++dt) {
        bf16x8 bv = ld8(Vts + (h * 32 + dt * 16 + lr) * VP + kt * 32 + kg * 8);
        o2[dt] = __builtin_amdgcn_mfma_f32_16x16x32_bf16(ap, bv, o2[dt], 0, 0, 0);
      }
    }
    if (kg < 2) {
#pragma unroll
      for (int dt = 0; dt < 2; ++dt)
#pragma unroll
        for (int rr = 0; rr < 4; ++rr)
          abuf[sst * 8 + kg * 4 + rr][h * 32 + dt * 16 + lr] =
              __float2bfloat16(o2[dt][rr]);
    }
  }
  __syncthreads();  // abuf complete

  f32x4 acc;
  float x2f[4];

  auto gemm_lds = [&](const __hip_bfloat16* W) {
    bf16x8 af[4];
#pragma unroll
    for (int ks = 0; ks < 4; ++ks)
      af[ks] = *reinterpret_cast<const bf16x8*>(&abuf[lr][ks * 32 + kg * 8]);
    int o = wid * 16 + lr;
    const __hip_bfloat16* wp = W + o * 128 + kg * 8;
    acc = f32x4{0, 0, 0, 0};
#pragma unroll
    for (int ks = 0; ks < 4; ++ks) {
      bf16x8 bfr = *reinterpret_cast<const bf16x8*>(wp + ks * 32);
      acc = __builtin_amdgcn_mfma_f32_16x16x32_bf16(af[ks], bfr, acc, 0, 0, 0);
    }
  };
  auto ln_store = [&](const float* g, const float* be) {
    float ps[4], pq[4];
#pragma unroll
    for (int rr = 0; rr < 4; ++rr) {
      ps[rr] = acc[rr];
      pq[rr] = acc[rr] * acc[rr];
    }
#pragma unroll
    for (int rr = 0; rr < 4; ++rr)
#pragma unroll
      for (int off = 1; off < 16; off <<= 1) {
        ps[rr] += __shfl_xor(ps[rr], off);
        pq[rr] += __shfl_xor(pq[rr], off);
      }
    if (lr == 0)
#pragma unroll
      for (int rr = 0; rr < 4; ++rr)
        red[wid][kg * 4 + rr] = make_float2(ps[rr], pq[rr]);
    __syncthreads();
    float mu[4], rs[4];
#pragma unroll
    for (int rr = 0; rr < 4; ++rr) {
      int r16 = kg * 4 + rr;
      float ssum = 0.f, qsum = 0.f;
#pragma unroll
      for (int w = 0; w < 8; ++w) {
        float2 a = red[w][r16];
        ssum += a.x;
        qsum += a.y;
      }
      mu[rr] = ssum * (1.f / 128.f);
      float var = qsum * (1.f / 128.f) - mu[rr] * mu[rr];
      rs[rr] = rsqrtf(var + 1e-5f);
    }
    int o = wid * 16 + lr;
    float gv = g[o], bev = be[o];
#pragma unroll
    for (int rr = 0; rr < 4; ++rr)
      abuf[kg * 4 + rr][o] =
          __float2bfloat16((acc[rr] - mu[rr]) * rs[rr] * gv + bev);
    __syncthreads();
  };

  gemm_lds(wproj);
  {
    float bv = bproj[wid * 16 + lr];
#pragma unroll
    for (int rr = 0; rr < 4; ++rr) acc[rr] += bv;
  }
  ln_store(g2, be2);

  gemm_lds(w1);
  {
    int o = wid * 16 + lr;
    float bv = b1[o];
#pragma unroll
    for (int rr = 0; rr < 4; ++rr) {
      int m = m0 + kg * 4 + rr;
      // residual = pre-LN x in NHWC = x[b][o][hw] (identical f32 values to old r)
      float v = acc[rr] + bv +
                x[(size_t)(m >> 12) * 524288 + (size_t)o * 4096 + (m & 4095)];
      x2f[rr] = v;
      acc[rr] = v;
    }
  }
  ln_store(g3, be3);

  gemm_lds(w2);
  {
    float bv = b2[wid * 16 + lr];
#pragma unroll
    for (int rr = 0; rr < 4; ++rr) acc[rr] = fmaxf(acc[rr] + bv, 0.f);
  }
  ln_store(g4, be4);

  gemm_lds(w3);
  {
    int o = wid * 16 + lr;
    float bv = b3[o];
#pragma unroll
    for (int rr = 0; rr < 4; ++rr) {
      int m = m0 + kg * 4 + rr;
      float v = acc[rr] + bv + x2f[rr];
      int bb = m >> 12, hw = m & 4095;
      out[(size_t)bb * 524288 + o * 4096 + hw] = v;
    }
  }
}

// ---------------- launch ----------------
extern "C" void kernel_launch(void* const* d_in, const int* in_sizes, int n_in,
                              void* d_out, int out_size, void* d_ws,
                              size_t ws_size, hipStream_t stream) {
  const float* x = (const float*)d_in[0];
  const float* g1 = (const float*)d_in[1];
  const float* be1 = (const float*)d_in[2];
  const float* g2 = (const float*)d_in[3];
  const float* be2 = (const float*)d_in[4];
  const float* g3 = (const float*)d_in[5];
  const float* be3 = (const float*)d_in[6];
  const float* g4 = (const float*)d_in[7];
  const float* be4 = (const float*)d_in[8];
  const float* qkv_w = (const float*)d_in[9];
  const float* qkv_b = (const float*)d_in[10];
  const float* rpb = (const float*)d_in[11];
  const float* proj_w = (const float*)d_in[12];
  const float* proj_b = (const float*)d_in[13];
  const float* w1 = (const float*)d_in[14];
  const float* bl1 = (const float*)d_in[15];
  const float* w2 = (const float*)d_in[16];
  const float* bl2 = (const float*)d_in[17];
  const float* w3 = (const float*)d_in[18];
  const float* bl3 = (const float*)d_in[19];

  char* ws = (char*)d_ws;
  __hip_bfloat16* wb = (__hip_bfloat16*)ws;               // [65536] tail weights bf16
  __hip_bfloat16* qkvb = (__hip_bfloat16*)(ws + 4456448); // [8192][384] bf16

  k_qkvcw<<<512, 512, 0, stream>>>(x, g1, be1, qkv_b, qkv_w, proj_w, w1, w2,
                                   w3, wb, qkvb);
  k_fuse3<<<512, 512, 0, stream>>>(qkvb, rpb, x, wb, proj_b, g2, be2, bl1, g3,
                                   be3, bl2, g4, be4, bl3, (float*)d_out);
}